// Round 1
// baseline (71.527 us; speedup 1.0000x reference)
//
#include <hip/hip_runtime.h>

// CRPS loss: out = mean(|y_pred - y|) - sum_{i,k,l}|x[i,k]-x[i,l]| / (N*2*M^2)
// N=4096 rows, M=256 ensemble.
//
// R9: single-dispatch fusion. R8's compute path (proven, absmax 0.0) is kept
// bit-identical; only the reduction plumbing changes:
//   - drop crps_final kernel + 1024-float ws partials entirely
//   - hipMemsetAsync(d_out, 0, 4) zeroes the (harness-poisoned) output
//   - each block: wave shuffle-reduce -> LDS -> single atomicAdd(out, bsum)
// Rationale (rocprof R8): timed graph is dominated by the harness's 256 MiB
// ws poison fill (~41 us @ 6.5 TB/s, top-5 dispatches are all
// fillBufferAligned). Our controllable budget is ~20 us = 2 kernel dispatches
// + exec. Removing one dispatch (~3 us overhead + ~2 us exec) for a 4-byte
// memset (~1 us) + 1024 pipelined same-address f32 atomics (~1-2 us) is the
// highest-confidence remaining lever.
//
// Pair accounting (64 tiles of 4 elems, lane t owns tile t):
//   s=1..31: tile-pair (t, t+s mod 64) -> each unordered inter-tile pair once
//   s=32:    each d=32 pair appears in both orders -> weight 0.5
//   intra-tile: 6 pairs, once
//   mix_ordered = 2*(m_intra + m_inter) + m32

constexpr int N_ROWS = 4096;
constexpr int M_COLS = 256;
constexpr int ROWS_PER_BLOCK = 4;                    // 4 waves x 1 row
constexpr int NUM_BLOCKS = N_ROWS / ROWS_PER_BLOCK;  // 1024

// m += |a - b| as exactly 2 VALU instrs (v_sub + v_add with |.| modifier).
__device__ __forceinline__ void abs_acc(float& m, float a, float b) {
    float t = a - b;
    asm("v_add_f32 %0, %0, |%1|" : "+v"(m) : "v"(t));
}

__global__ __launch_bounds__(256)
void crps_fused(const float* __restrict__ y_pred,
                const float* __restrict__ y,
                float* __restrict__ out) {
    __shared__ __align__(16) float4 rows[ROWS_PER_BLOCK][2 * M_COLS / 4];
    __shared__ float wsum[ROWS_PER_BLOCK];

    const int wave = threadIdx.x >> 6;               // 0..3 -> row of block
    const int lane = threadIdx.x & 63;
    const int row  = blockIdx.x * ROWS_PER_BLOCK + wave;

    // Lane owns tile t=lane (elements 4t..4t+3); stage row twice so rotated
    // reads r4[lane+s] never wrap mod 64.
    const float4 xk = reinterpret_cast<const float4*>(y_pred + row * M_COLS)[lane];
    rows[wave][lane]      = xk;
    rows[wave][lane + 64] = xk;
    const float yi = y[row];                         // wave-uniform

    const float xo[4] = {xk.x, xk.y, xk.z, xk.w};

    // MAE term.
    float mae = 0.0f;
    #pragma unroll
    for (int j = 0; j < 4; ++j) abs_acc(mae, xo[j], yi);

    // 4 independent accumulator chains; intra-tile pairs spread across them.
    float m[4] = {0.0f, 0.0f, 0.0f, 0.0f};
    abs_acc(m[0], xo[0], xo[1]); abs_acc(m[1], xo[0], xo[2]);
    abs_acc(m[2], xo[0], xo[3]); abs_acc(m[3], xo[1], xo[2]);
    abs_acc(m[0], xo[1], xo[3]); abs_acc(m[1], xo[2], xo[3]);

    // No barrier needed: wave reads only LDS it wrote itself (same-wave DS
    // ordering) — pattern proven in R3/R4/R6.
    const float4* r4 = &rows[wave][lane];            // r4[s] -> imm offset 16s

    // s = 1..24: exactly 3 chunks of 8 — NO remainder epilogue.
    #pragma unroll 8
    for (int s = 1; s <= 24; ++s) {
        const float4 v = r4[s];
        #pragma unroll
        for (int j = 0; j < 4; ++j) {
            abs_acc(m[j], xo[j], v.x); abs_acc(m[j], xo[j], v.y);
            abs_acc(m[j], xo[j], v.z); abs_acc(m[j], xo[j], v.w);
        }
    }
    // s = 25..31: straight-line full unroll — NO remainder epilogue.
    #pragma unroll
    for (int s = 25; s <= 31; ++s) {
        const float4 v = r4[s];
        #pragma unroll
        for (int j = 0; j < 4; ++j) {
            abs_acc(m[j], xo[j], v.x); abs_acc(m[j], xo[j], v.y);
            abs_acc(m[j], xo[j], v.z); abs_acc(m[j], xo[j], v.w);
        }
    }
    // s = 32: every pair counted in both orders across the wave -> weight 0.5.
    float m32 = 0.0f;
    {
        const float4 v = r4[32];
        #pragma unroll
        for (int j = 0; j < 4; ++j) {
            abs_acc(m32, xo[j], v.x); abs_acc(m32, xo[j], v.y);
            abs_acc(m32, xo[j], v.z); abs_acc(m32, xo[j], v.w);
        }
    }

    const float msum = (m[0] + m[1]) + (m[2] + m[3]);

    // mix contribution = (2*msum + m32)/(2*N*M^2) = (msum + 0.5*m32)/(N*M^2)
    constexpr float mae_scale = 1.0f / ((float)N_ROWS * (float)M_COLS);
    constexpr float inv_NM2   = 1.0f / ((float)N_ROWS * (float)M_COLS * (float)M_COLS);
    float part = mae * mae_scale - (msum + 0.5f * m32) * inv_NM2;

    // Wave reduction -> block sum -> ONE device-scope atomic per block.
    #pragma unroll
    for (int off = 32; off > 0; off >>= 1)
        part += __shfl_down(part, off, 64);

    if (lane == 0) wsum[wave] = part;
    __syncthreads();
    if (threadIdx.x == 0)
        atomicAdd(out, (wsum[0] + wsum[1]) + (wsum[2] + wsum[3]));
}

extern "C" void kernel_launch(void* const* d_in, const int* in_sizes, int n_in,
                              void* d_out, int out_size, void* d_ws, size_t ws_size,
                              hipStream_t stream) {
    const float* y_pred = (const float*)d_in[0];
    const float* y      = (const float*)d_in[1];
    float* out          = (float*)d_out;
    (void)d_ws; (void)ws_size;                       // ws no longer used

    // Zero the poisoned output, then accumulate into it with block atomics.
    // (hipMemsetAsync is graph-capturable; the harness's own reset uses it.)
    hipMemsetAsync(out, 0, sizeof(float), stream);
    crps_fused<<<NUM_BLOCKS, 256, 0, stream>>>(y_pred, y, out);
}

// Round 2
// 62.812 us; speedup vs baseline: 1.1387x; 1.1387x over previous
//
#include <hip/hip_runtime.h>

// CRPS loss: out = mean(|y_pred - y|) - sum_{i,k,l}|x[i,k]-x[i,l]| / (N*2*M^2)
// N=4096 rows, M=256 ensemble.
//
// R10: sort-based mix term + revert to R8's proven two-kernel plumbing.
//
// R9 post-mortem: single-dispatch + memset + same-address atomicAdd REGRESSED
// 62.0 -> 71.5 us. The 4-byte memset is its own fill dispatch (no dispatch
// win) and 1024 device-scope f32 atomics to ONE address from 8 non-coherent
// XCDs serialize at a single coherence point (~5-8 us tail). Plumbing
// reverted to R8's partial[] -> crps_final plain-store scheme (proven 62.0).
//
// R10 change (compute): for a sorted row, sum_{k<l}|x_k-x_l| =
// sum_e (2e - M + 1) * x_(e). Full bitonic sort of 256 values per wave
// (normalized network, every comparator keeps min at the lower global index):
//   element e = 4*lane + r  (lane 0..63 holds 4 values in regs)
//   k=2,4 flips + j<=2 cleaners: in-lane, static min/max (15 stages)
//   k>=8 flips (partner = e^(k-1) -> lane^((k>>2)-1), reg^3) and j>=4
//   cleaners (partner = e^j -> lane^(j>>2), same reg): __shfl_xor + select
//   (21 stages, 84 shuffles total)
// ~333 VALU + 84 shfl vs ~1046 VALU for the pairwise scheme; LDS row staging
// is gone entirely. Network hand-verified on 4- and 8-element examples.
// f32 reassociation error in the final scalar ~1e-10 (weights |w|<=255,
// per-row sums ~4e4, scaled by 1/(N*M^2)).

constexpr int N_ROWS = 4096;
constexpr int M_COLS = 256;
constexpr int ROWS_PER_BLOCK = 4;                    // 4 waves x 1 row
constexpr int NUM_BLOCKS = N_ROWS / ROWS_PER_BLOCK;  // 1024

// m += |a - b| as exactly 2 VALU instrs (v_sub + v_add with |.| modifier).
__device__ __forceinline__ void abs_acc(float& m, float a, float b) {
    float t = a - b;
    asm("v_add_f32 %0, %0, |%1|" : "+v"(m) : "v"(t));
}

__global__ __launch_bounds__(256)
void crps_partial(const float* __restrict__ y_pred,
                  const float* __restrict__ y,
                  float* __restrict__ partial) {
    __shared__ float wsum[ROWS_PER_BLOCK];

    const int wave = threadIdx.x >> 6;               // 0..3 -> row of block
    const int lane = threadIdx.x & 63;
    const int row  = blockIdx.x * ROWS_PER_BLOCK + wave;

    const float4 xk = reinterpret_cast<const float4*>(y_pred + row * M_COLS)[lane];
    const float yi = y[row];                         // wave-uniform

    float v[4] = {xk.x, xk.y, xk.z, xk.w};

    // MAE term on the ORIGINAL values (before sort scrambles them).
    float mae = 0.0f;
    #pragma unroll
    for (int j = 0; j < 4; ++j) abs_acc(mae, v[j], yi);

    // ---- bitonic sort: 256 values across the wave, ascending in e=4*lane+r.
    // Static in-lane comparator: keep min at the lower register index.
    auto CE = [&](int a, int b) {
        const float mn = fminf(v[a], v[b]);
        const float mx = fmaxf(v[a], v[b]);
        v[a] = mn; v[b] = mx;
    };

    // k=2: flip (0,1),(2,3)
    CE(0,1); CE(2,3);
    // k=4: flip (0,3),(1,2) then j=1 cleaner (0,1),(2,3)
    CE(0,3); CE(1,2);
    CE(0,1); CE(2,3);

    #pragma unroll
    for (int k = 8; k <= 256; k <<= 1) {
        {   // flip: partner = e ^ (k-1)  ->  lane ^ ((k>>2)-1), reg ^ 3.
            // keep min where e & (k/2) == 0 -> lane bit (k>>3).
            const int  lm  = (k >> 2) - 1;
            const bool isl = (lane & (k >> 3)) == 0;
            const float p0 = __shfl_xor(v[3], lm, 64);
            const float p1 = __shfl_xor(v[2], lm, 64);
            const float p2 = __shfl_xor(v[1], lm, 64);
            const float p3 = __shfl_xor(v[0], lm, 64);
            v[0] = isl ? fminf(v[0], p0) : fmaxf(v[0], p0);
            v[1] = isl ? fminf(v[1], p1) : fmaxf(v[1], p1);
            v[2] = isl ? fminf(v[2], p2) : fmaxf(v[2], p2);
            v[3] = isl ? fminf(v[3], p3) : fmaxf(v[3], p3);
        }
        // cross-lane cleaners: partner = e ^ j -> lane ^ (j>>2), same reg.
        // keep min where e & j == 0 -> lane bit (j>>2).
        #pragma unroll
        for (int j = k >> 2; j >= 4; j >>= 1) {
            const int  lm  = j >> 2;
            const bool isl = (lane & lm) == 0;
            const float p0 = __shfl_xor(v[0], lm, 64);
            const float p1 = __shfl_xor(v[1], lm, 64);
            const float p2 = __shfl_xor(v[2], lm, 64);
            const float p3 = __shfl_xor(v[3], lm, 64);
            v[0] = isl ? fminf(v[0], p0) : fmaxf(v[0], p0);
            v[1] = isl ? fminf(v[1], p1) : fmaxf(v[1], p1);
            v[2] = isl ? fminf(v[2], p2) : fmaxf(v[2], p2);
            v[3] = isl ? fminf(v[3], p3) : fmaxf(v[3], p3);
        }
        // j=2 cleaner: (0,2),(1,3); j=1 cleaner: (0,1),(2,3) — in-lane, static.
        CE(0,2); CE(1,3);
        CE(0,1); CE(2,3);
    }

    // Sorted: rank of v[r] is e = 4*lane + r.  Weight w_e = 2e - (M-1).
    // sum_{k<l}(x_(l)-x_(k)) = sum_e w_e * x_(e);
    // ordered mix sum = 2 * that; ref divides by (N*2*M^2)
    //   -> mix contribution = (sum_e w_e x_(e)) / (N*M^2).
    const float wbase = (float)(8 * lane - 255);     // w at r=0
    float mix;
    mix = v[0] * wbase;
    mix = fmaf(v[1], wbase + 2.0f, mix);
    mix = fmaf(v[2], wbase + 4.0f, mix);
    mix = fmaf(v[3], wbase + 6.0f, mix);

    constexpr float mae_scale = 1.0f / ((float)N_ROWS * (float)M_COLS);
    constexpr float inv_NM2   = 1.0f / ((float)N_ROWS * (float)M_COLS * (float)M_COLS);
    float part = mae * mae_scale - mix * inv_NM2;

    // Wave reduction -> block partial (no atomics, no fences) — R8 plumbing.
    #pragma unroll
    for (int off = 32; off > 0; off >>= 1)
        part += __shfl_down(part, off, 64);

    if (lane == 0) wsum[wave] = part;
    __syncthreads();
    if (threadIdx.x == 0)
        partial[blockIdx.x] = (wsum[0] + wsum[1]) + (wsum[2] + wsum[3]);
}

__global__ __launch_bounds__(256)
void crps_final(const float* __restrict__ partial, float* __restrict__ out) {
    __shared__ float wsum[4];
    const int t = threadIdx.x;
    const float4 v4 = reinterpret_cast<const float4*>(partial)[t];
    float v = (v4.x + v4.y) + (v4.z + v4.w);
    #pragma unroll
    for (int off = 32; off > 0; off >>= 1)
        v += __shfl_down(v, off, 64);
    if ((t & 63) == 0) wsum[t >> 6] = v;
    __syncthreads();
    if (t == 0)
        *out = (wsum[0] + wsum[1]) + (wsum[2] + wsum[3]);
}

extern "C" void kernel_launch(void* const* d_in, const int* in_sizes, int n_in,
                              void* d_out, int out_size, void* d_ws, size_t ws_size,
                              hipStream_t stream) {
    const float* y_pred = (const float*)d_in[0];
    const float* y      = (const float*)d_in[1];
    float* out          = (float*)d_out;
    float* ws           = (float*)d_ws;              // 1024 floats used

    crps_partial<<<NUM_BLOCKS, 256, 0, stream>>>(y_pred, y, ws);
    crps_final<<<1, 256, 0, stream>>>(ws, out);
}